// Round 7
// baseline (1154.762 us; speedup 1.0000x reference)
//
#include <hip/hip_runtime.h>
#include <hip/hip_bf16.h>
#include <math.h>
#include <stdint.h>

#define NL 6
#define NB 2
#define ST 1024
#define ND 768
#define NH 12
#define HD 64
#define NFF 3072
#define NV 50257
#define ND3 2304
#define NM (NB * ST) // 2048

typedef short bf16x4 __attribute__((ext_vector_type(4)));
typedef short bf16x8 __attribute__((ext_vector_type(8)));
typedef float f32x4  __attribute__((ext_vector_type(4)));

typedef __attribute__((address_space(3))) void as3_void;
typedef __attribute__((address_space(1))) void as1_void;

// async global->LDS, 16B per lane; LDS dest is wave-uniform base + lane*16
__device__ __forceinline__ void async_copy16(const void* g, void* lds) {
  __builtin_amdgcn_global_load_lds((const as1_void*)(uintptr_t)g,
                                   (as3_void*)(uint32_t)(uintptr_t)lds,
                                   16, 0, 0);
}

__device__ __forceinline__ unsigned short f2bf(float f) {
  union { float f; uint32_t u; } v; v.f = f;
  return (unsigned short)((v.u + 0x7fffu + ((v.u >> 16) & 1u)) >> 16);
}

__device__ __forceinline__ bf16x8 frag16(const unsigned short* p) {
  return *(const bf16x8*)p;   // single ds_read_b128
}

// counted-vmcnt barrier: wait until only the NEXT tile's own loads are in
// flight, then raw barrier (NO __syncthreads -> no vmcnt(0) drain).
template <int N>
__device__ __forceinline__ void wait_vm_barrier() {
  if constexpr (N == 8)      asm volatile("s_waitcnt vmcnt(8)\n\ts_barrier" ::: "memory");
  else if constexpr (N == 6) asm volatile("s_waitcnt vmcnt(6)\n\ts_barrier" ::: "memory");
  else if constexpr (N == 4) asm volatile("s_waitcnt vmcnt(4)\n\ts_barrier" ::: "memory");
  else                       asm volatile("s_waitcnt vmcnt(0)\n\ts_barrier" ::: "memory");
}
__device__ __forceinline__ void lgkm_barrier() {
  asm volatile("s_waitcnt lgkmcnt(0)\n\ts_barrier" ::: "memory");
}

#define MFMA(a, b, c) __builtin_amdgcn_mfma_f32_16x16x32_bf16((a), (b), (c), 0, 0, 0)

__device__ __forceinline__ float gelu_buggy(float x) {
  // faithful to ref: 0.5*x*(1+tanh(sqrt(2/pi) * 0.044715 * x^4))
  const float c = 0.7978845608028654f;
  float x2 = x * x;
  return 0.5f * x * (1.0f + tanhf(c * 0.044715f * x2 * x2));
}

enum { EP_QKV = 0, EP_PROJ, EP_FF1, EP_FF2, EP_HEAD };

// C[M,N] = A[M,K] @ BT[N,K]^T + bias, fused epilogue.
// BK-templated (32/64), double-buffered LDS, counted-vmcnt pipeline.
// Swizzle (bank-exact): granule(row) = (row mod 128B part) x (slot ^ swz).
//   BK=64: rows are 128B -> swz = row&7          (8 granules, 2-way, free)
//   BK=32: rows are  64B -> swz = (row>>1)&3     (row&1 supplies the other
//          granule bit; using row&3 here was R6's 4-way-conflict bug)
// Same XOR on staging source and ds_read; identical slot->k map for A and
// B, so the K permutation cancels in the MFMA dot product.
// EP_QKV additionally scatters the V third into vT[b][h][d][t].
template <int EPI, int TM, int TN, int WN, int NW, int BK>
__global__ __launch_bounds__(NW * 64)
void gemm_bt(const unsigned short* __restrict__ A,
             const unsigned short* __restrict__ BT,
             const float* __restrict__ bias,
             float* __restrict__ Cf,
             unsigned short* __restrict__ Cb,
             const float* __restrict__ resid,
             unsigned short* __restrict__ vT,
             int M, int N, int K)
{
  constexpr int WM = NW / WN;
  constexpr int FM = TM / WM / 16;     // A frags per wave
  constexpr int FN = TN / WN / 16;     // B frags per wave
  constexpr int SL = BK / 8;           // 16B slots per row (8 or 4)
  constexpr int RS = (BK == 32) ? 1 : 0; // swizzle row shift (see header)
  constexpr int RPC = 1024 / (BK * 2); // rows per 1KB staging chunk
  constexpr int CA = TM / RPC / NW;    // A staging chunks per wave
  constexpr int CB = TN / RPC / NW;
  constexpr int LPT = CA + CB;         // loads per thread per K-step
  constexpr int KK = BK / 32;          // mfma k-slices per K-step
  __shared__ __align__(16) unsigned short As[2][TM * BK];
  __shared__ __align__(16) unsigned short Bs[2][TN * BK];
  const int tid = threadIdx.x;
  const int w = tid >> 6, l = tid & 63;
  const int g = l >> 4, r = l & 15;
  const int wm = (w / WN) * (FM * 16);
  const int wn = (w % WN) * (FN * 16);

  // bijective XCD-aware swizzle (all grids here have nwg % 8 == 0)
  const int nbx = gridDim.x;
  const int nwg = nbx * gridDim.y;
  int bid = blockIdx.y * nbx + blockIdx.x;
  if ((nwg & 7) == 0) bid = (bid & 7) * (nwg >> 3) + (bid >> 3);
  const int m0 = (bid % nbx) * TM, n0 = (bid / nbx) * TN;

  // staging: chunk = RPC rows x BK*2 bytes; lanes-per-row = BK/8 (16B each).
  const int sr = l / (BK / 8);         // row within chunk
  const int se = ((l & (SL - 1)) ^ ((sr >> RS) & (SL - 1))) * 8;
  long aoff[CA];
  long boff[CB];
#pragma unroll
  for (int c = 0; c < CA; ++c) {
    const int arow = (w * CA + c) * RPC + sr;
    aoff[c] = (long)(m0 + arow) * K + se;
  }
#pragma unroll
  for (int c = 0; c < CB; ++c) {
    int brow = n0 + (w * CB + c) * RPC + sr;
    if (brow > N - 1) brow = N - 1;
    boff[c] = (long)brow * K + se;
  }

  f32x4 acc[FM][FN] = {};

  auto stage = [&](int t, int buf) {
    const long k0 = (long)t * BK;
#pragma unroll
    for (int c = 0; c < CA; ++c)
      async_copy16(A + aoff[c] + k0, &As[buf][(w * CA + c) * 512]);
#pragma unroll
    for (int c = 0; c < CB; ++c)
      async_copy16(BT + boff[c] + k0, &Bs[buf][(w * CB + c) * 512]);
  };

  auto compute = [&](int buf) {
#pragma unroll
    for (int kk = 0; kk < KK; ++kk) {
      bf16x8 af[FM], bf[FN];
#pragma unroll
      for (int mi = 0; mi < FM; ++mi)
        af[mi] = frag16(&As[buf][(wm + mi * 16 + r) * BK +
                                 (((kk * 4 + g) ^ ((r >> RS) & (SL - 1))) * 8)]);
#pragma unroll
      for (int ni = 0; ni < FN; ++ni)
        bf[ni] = frag16(&Bs[buf][(wn + ni * 16 + r) * BK +
                                 (((kk * 4 + g) ^ ((r >> RS) & (SL - 1))) * 8)]);
      __builtin_amdgcn_s_setprio(1);
#pragma unroll
      for (int mi = 0; mi < FM; ++mi)
#pragma unroll
        for (int ni = 0; ni < FN; ++ni)
          acc[mi][ni] = MFMA(af[mi], bf[ni], acc[mi][ni]);
      __builtin_amdgcn_s_setprio(0);
    }
  };

  const int nt = K / BK;
  stage(0, 0);
  for (int t = 0; t < nt - 1; ++t) {
    stage(t + 1, (t + 1) & 1);         // issued BEFORE the wait: stays in flight
    wait_vm_barrier<LPT>();            // tile t landed (all waves); t+1 pending
    compute(t & 1);
    lgkm_barrier();                    // readers done before buf reuse
  }
  wait_vm_barrier<0>();                // drain last tile
  compute((nt - 1) & 1);

#pragma unroll
  for (int mi = 0; mi < FM; ++mi) {
#pragma unroll
    for (int ni = 0; ni < FN; ++ni) {
      const int col = n0 + wn + ni * 16 + r;
      if (EPI == EP_HEAD && col >= N) continue;
      const float bb = bias[col];
      if (EPI == EP_QKV && col >= 2 * ND) {
        // V third -> vT[b][h][d][t] (bf16), 4 consecutive t per lane
        const int hv = (col - 2 * ND) >> 6, d = (col - 2 * ND) & 63;
        short4 vv;
#pragma unroll
        for (int q = 0; q < 4; ++q)
          vv[q] = (short)f2bf(acc[mi][ni][q] + bb);
        const int row = m0 + wm + mi * 16 + g * 4;
        const int bb_ = row >> 10, t4 = row & 1023;
        *(short4*)&vT[(((long)bb_ * NH + hv) * HD + d) * ST + t4] = vv;
        continue;
      }
#pragma unroll
      for (int q = 0; q < 4; ++q) {
        const int row = m0 + wm + mi * 16 + g * 4 + q;
        float v = acc[mi][ni][q] + bb;
        if constexpr (EPI == EP_QKV) {
          Cb[(long)row * N + col] = f2bf(v);
        } else if constexpr (EPI == EP_PROJ) {
          Cf[(long)row * N + col] = v;
        } else if constexpr (EPI == EP_FF1) {
          Cb[(long)row * N + col] = f2bf(gelu_buggy(v));
        } else if constexpr (EPI == EP_FF2) {
          float o = v + resid[(long)row * N + col];
          Cf[(long)row * N + col] = o;
          Cb[(long)row * N + col] = f2bf(o);
        } else { // EP_HEAD
          Cf[(long)row * N + col] = v;
        }
      }
    }
  }
}

// Flash attention, no mask. Block = 4 waves, one (b,h) x 64 q-rows.
// Each wave owns 16 q-rows. LDS stride 72 avoids D=64 bank conflicts.
// V^T comes pre-transposed from the QKV epilogue (vT[b][h][d][t]).
__global__ __launch_bounds__(256)
void attn_kernel(const unsigned short* __restrict__ qkv,
                 const unsigned short* __restrict__ vT,
                 unsigned short* __restrict__ y)
{
  constexpr int LS = 72;
  __shared__ __align__(16) unsigned short Qs[64 * LS];
  __shared__ __align__(16) unsigned short Ks[64 * LS];
  __shared__ __align__(16) unsigned short Vt[64 * LS];
  __shared__ __align__(16) unsigned short Ps[64 * LS];
  const int tid = threadIdx.x;
  const int w = tid >> 6, l = tid & 63;
  const int g = l >> 4, r = l & 15;
  const int q0 = blockIdx.x * 64;
  const int b = blockIdx.y / NH, h = blockIdx.y % NH;
  const long rb = (long)b * ST;
  const long vbase = ((long)b * NH + h) * HD * ST;
  const int srow = tid >> 3, sc8 = (tid & 7) * 8;

  // stage Q tile [64 rows][64 dims]
#pragma unroll
  for (int p = 0; p < 2; ++p) {
    const int row = p * 32 + srow;
    bf16x8 v = *(const bf16x8*)&qkv[(rb + q0 + row) * ND3 + h * HD + sc8];
    *(bf16x8*)&Qs[row * LS + sc8] = v;
  }
  __syncthreads();
  // Q fragments hoisted out of the KV loop (Qs is never overwritten)
  bf16x8 aq[2];
#pragma unroll
  for (int kk = 0; kk < 2; ++kk)
    aq[kk] = *(const bf16x8*)&Qs[(w * 16 + r) * LS + kk * 32 + g * 8];

  float m_run[4] = {-1e30f, -1e30f, -1e30f, -1e30f};
  float l_run[4] = {0.f, 0.f, 0.f, 0.f};
  f32x4 acc_o[4] = {};

  for (int kt = 0; kt < ST / 64; ++kt) {
#pragma unroll
    for (int p = 0; p < 2; ++p) {
      const int row = p * 32 + srow;
      *(bf16x8*)&Ks[row * LS + sc8] =
          *(const bf16x8*)&qkv[(rb + kt * 64 + row) * ND3 + ND + h * HD + sc8];
      *(bf16x8*)&Vt[row * LS + sc8] =
          *(const bf16x8*)&vT[vbase + (long)row * ST + kt * 64 + sc8];
    }
    __syncthreads();

    // S = Q K^T for this wave's 16 q-rows
    f32x4 s_acc[4] = {};
#pragma unroll
    for (int kk = 0; kk < 2; ++kk) {
#pragma unroll
      for (int ni = 0; ni < 4; ++ni) {
        bf16x8 bk = *(const bf16x8*)&Ks[(ni * 16 + r) * LS + kk * 32 + g * 8];
        s_acc[ni] = MFMA(aq[kk], bk, s_acc[ni]);
      }
    }

    // online softmax; lane owns rows g*4+q at cols ni*16+r
    float mloc[4];
#pragma unroll
    for (int q = 0; q < 4; ++q) {
      float mx = fmaxf(fmaxf(s_acc[0][q], s_acc[1][q]), fmaxf(s_acc[2][q], s_acc[3][q]));
      mloc[q] = mx * 0.125f;
    }
#pragma unroll
    for (int mask = 1; mask < 16; mask <<= 1)
#pragma unroll
      for (int q = 0; q < 4; ++q)
        mloc[q] = fmaxf(mloc[q], __shfl_xor(mloc[q], mask, 64));

    float alpha[4], psum[4] = {0.f, 0.f, 0.f, 0.f};
#pragma unroll
    for (int q = 0; q < 4; ++q) {
      const float mn = fmaxf(m_run[q], mloc[q]);
      alpha[q] = __expf(m_run[q] - mn);
      m_run[q] = mn;
    }
#pragma unroll
    for (int ni = 0; ni < 4; ++ni)
#pragma unroll
      for (int q = 0; q < 4; ++q) {
        const float p = __expf(s_acc[ni][q] * 0.125f - m_run[q]);
        psum[q] += p;
        Ps[(w * 16 + g * 4 + q) * LS + ni * 16 + r] = f2bf(p);
      }
#pragma unroll
    for (int mask = 1; mask < 16; mask <<= 1)
#pragma unroll
      for (int q = 0; q < 4; ++q) psum[q] += __shfl_xor(psum[q], mask, 64);
#pragma unroll
    for (int q = 0; q < 4; ++q) l_run[q] = l_run[q] * alpha[q] + psum[q];
#pragma unroll
    for (int ni = 0; ni < 4; ++ni)
#pragma unroll
      for (int q = 0; q < 4; ++q) acc_o[ni][q] *= alpha[q];

    // wave-local P writes must land before reading as MFMA A-operand
    asm volatile("s_waitcnt lgkmcnt(0)" ::: "memory");
    __builtin_amdgcn_sched_barrier(0);

    // O += P @ V
#pragma unroll
    for (int kk = 0; kk < 2; ++kk) {
      bf16x8 ap = *(const bf16x8*)&Ps[(w * 16 + r) * LS + kk * 32 + g * 8];
#pragma unroll
      for (int ni = 0; ni < 4; ++ni) {
        bf16x8 bv = *(const bf16x8*)&Vt[(ni * 16 + r) * LS + kk * 32 + g * 8];
        acc_o[ni] = MFMA(ap, bv, acc_o[ni]);
      }
    }
    __syncthreads();  // all reads of Ks/Vt done before next stage
  }

#pragma unroll
  for (int ni = 0; ni < 4; ++ni)
#pragma unroll
    for (int q = 0; q < 4; ++q) {
      const int row = q0 + w * 16 + g * 4 + q;
      const int col = h * HD + ni * 16 + r;
      y[(rb + row) * ND + col] = f2bf(acc_o[ni][q] / l_run[q]);
    }
}

// LayerNorm over D=768 (+optional residual add); writes fp32 and/or bf16.
template <bool RESID>
__global__ __launch_bounds__(256)
void ln_kernel(const float* __restrict__ in, const float* __restrict__ resid,
               const float* __restrict__ gamma, const float* __restrict__ beta,
               float* __restrict__ out_f, unsigned short* __restrict__ out_b)
{
  __shared__ float wred[8];
  const int row = blockIdx.x, tid = threadIdx.x;
  float v[3];
#pragma unroll
  for (int j = 0; j < 3; ++j) v[j] = in[(long)row * ND + tid + j * 256];
  float s = v[0] + v[1] + v[2];
#pragma unroll
  for (int m = 1; m < 64; m <<= 1) s += __shfl_xor(s, m, 64);
  if ((tid & 63) == 0) wred[tid >> 6] = s;
  __syncthreads();
  const float mean = (wred[0] + wred[1] + wred[2] + wred[3]) * (1.0f / ND);
  float d[3];
#pragma unroll
  for (int j = 0; j < 3; ++j) d[j] = v[j] - mean;
  float s2 = d[0] * d[0] + d[1] * d[1] + d[2] * d[2];
#pragma unroll
  for (int m = 1; m < 64; m <<= 1) s2 += __shfl_xor(s2, m, 64);
  if ((tid & 63) == 0) wred[4 + (tid >> 6)] = s2;
  __syncthreads();
  const float var = (wred[4] + wred[5] + wred[6] + wred[7]) * (1.0f / ND);
  const float rstd = rsqrtf(var + 1e-5f);
#pragma unroll
  for (int j = 0; j < 3; ++j) {
    const int c = tid + j * 256;
    float o = d[j] * rstd * gamma[c] + beta[c];
    if (RESID) o += resid[(long)row * ND + c];
    if (out_f) out_f[(long)row * ND + c] = o;
    if (out_b) out_b[(long)row * ND + c] = f2bf(o);
  }
}

__global__ __launch_bounds__(256)
void embed_kernel(const int* __restrict__ ids, const float* __restrict__ wte,
                  const float* __restrict__ wpe, float* __restrict__ x,
                  unsigned short* __restrict__ xb)
{
  const int t = blockIdx.x, tid = threadIdx.x;
  const int tok = ids[t];
  const int pos = t & (ST - 1);
#pragma unroll
  for (int j = 0; j < 3; ++j) {
    const int c = tid + j * 256;
    const float v = wte[(long)tok * ND + c] + wpe[(long)pos * ND + c];
    x[(long)t * ND + c] = v;
    xb[(long)t * ND + c] = f2bf(v);
  }
}

// fp32 [z][R][C] -> bf16 [z][C][R], 64(R)x32(C) tiles, coalesced both sides.
__global__ __launch_bounds__(256)
void transpose_bf16(const float* __restrict__ in, unsigned short* __restrict__ out,
                    int R, int C)
{
  __shared__ float tile[64][33];
  const long z = (long)blockIdx.z * R * C;
  const int c0 = blockIdx.x * 32, r0 = blockIdx.y * 64;
  const int tx = threadIdx.x & 31, ty = threadIdx.x >> 5;   // read indexing
#pragma unroll
  for (int j = 0; j < 8; ++j) {
    const int rr = r0 + j * 8 + ty, cc = c0 + tx;
    if (cc < C) tile[j * 8 + ty][tx] = in[z + (long)rr * C + cc];
  }
  __syncthreads();
  const int rx = threadIdx.x & 63, cy = threadIdx.x >> 6;   // write indexing
#pragma unroll
  for (int j = 0; j < 8; ++j) {
    const int cc = c0 + j * 4 + cy;
    if (cc < C) out[z + (long)cc * R + r0 + rx] = f2bf(tile[rx][j * 4 + cy]);
  }
}

extern "C" void kernel_launch(void* const* d_in, const int* in_sizes, int n_in,
                              void* d_out, int out_size, void* d_ws, size_t ws_size,
                              hipStream_t stream)
{
  const int*   ids    = (const int*)d_in[0];
  const float* wte    = (const float*)d_in[1];
  const float* wpe    = (const float*)d_in[2];
  const float* W_qkv  = (const float*)d_in[3];
  const float* b_qkv  = (const float*)d_in[4];
  const float* W_o    = (const float*)d_in[5];
  const float* b_o    = (const float*)d_in[6];
  const float* ln1_g  = (const float*)d_in[7];
  const float* ln1_b  = (const float*)d_in[8];
  const float* W1     = (const float*)d_in[9];
  const float* b1     = (const float*)d_in[10];
  const float* W2     = (const float*)d_in[11];
  const float* b2     = (const float*)d_in[12];
  const float* lnf_g  = (const float*)d_in[13];
  const float* lnf_b  = (const float*)d_in[14];
  const float* W_head = (const float*)d_in[15];
  const float* b_head = (const float*)d_in[16];
  float* out = (float*)d_out;
  (void)in_sizes; (void)n_in; (void)out_size; (void)ws_size;

  char* ws = (char*)d_ws;
  size_t off = 0;
  auto alloc = [&](size_t bytes) -> void* {
    void* p = (void*)(ws + off);
    off = (off + bytes + 255) & ~(size_t)255;
    return p;
  };
  unsigned short* wqkvT = (unsigned short*)alloc((size_t)NL * ND3 * ND * 2);
  unsigned short* woT   = (unsigned short*)alloc((size_t)NL * ND * ND * 2);
  unsigned short* w1T   = (unsigned short*)alloc((size_t)NL * NFF * ND * 2);
  unsigned short* w2T   = (unsigned short*)alloc((size_t)NL * ND * NFF * 2);
  unsigned short* whT   = (unsigned short*)alloc((size_t)NV * ND * 2);
  float*          xf    = (float*)alloc((size_t)NM * ND * 4);
  unsigned short* xb    = (unsigned short*)alloc((size_t)NM * ND * 2);
  unsigned short* qkvb  = (unsigned short*)alloc((size_t)NM * ND3 * 2);
  unsigned short* yb    = (unsigned short*)alloc((size_t)NM * ND * 2);
  float*          aof   = (float*)alloc((size_t)NM * ND * 4);
  unsigned short* h1b   = (unsigned short*)alloc((size_t)NM * NFF * 2);
  unsigned short* xlnb  = (unsigned short*)alloc((size_t)NM * ND * 2);
  unsigned short* vtb   = (unsigned short*)alloc((size_t)NB * NH * HD * ST * 2);

  dim3 tb(256);
  dim3 tb128(128);
  dim3 tb512(512);
  // weight convert+transpose (fp32 [K][N] -> bf16 [N][K])
  transpose_bf16<<<dim3(ND3 / 32, ND / 64, NL), tb, 0, stream>>>(W_qkv, wqkvT, ND, ND3);
  transpose_bf16<<<dim3(ND / 32, ND / 64, NL), tb, 0, stream>>>(W_o, woT, ND, ND);
  transpose_bf16<<<dim3(NFF / 32, ND / 64, NL), tb, 0, stream>>>(W1, w1T, ND, NFF);
  transpose_bf16<<<dim3(ND / 32, NFF / 64, NL), tb, 0, stream>>>(W2, w2T, NFF, ND);
  transpose_bf16<<<dim3((NV + 31) / 32, ND / 64, 1), tb, 0, stream>>>(W_head, whT, ND, NV);

  embed_kernel<<<dim3(NM), tb, 0, stream>>>(ids, wte, wpe, xf, xb);

  for (int l = 0; l < NL; ++l) {
    gemm_bt<EP_QKV, 128, 128, 2, 4, 64><<<dim3(NM / 128, ND3 / 128), tb, 0, stream>>>(
        xb, wqkvT + (size_t)l * ND3 * ND, b_qkv + (size_t)l * ND3,
        nullptr, qkvb, nullptr, vtb, NM, ND3, ND);
    attn_kernel<<<dim3(ST / 64, NB * NH), tb, 0, stream>>>(qkvb, vtb, yb);
    gemm_bt<EP_PROJ, 64, 64, 2, 2, 64><<<dim3(NM / 64, ND / 64), tb128, 0, stream>>>(
        yb, woT + (size_t)l * ND * ND, b_o + (size_t)l * ND,
        aof, nullptr, nullptr, nullptr, NM, ND, ND);
    ln_kernel<true><<<dim3(NM), tb, 0, stream>>>(
        aof, xf, ln1_g + (size_t)l * ND, ln1_b + (size_t)l * ND, xf, xb);
    gemm_bt<EP_FF1, 128, 128, 2, 4, 64><<<dim3(NM / 128, NFF / 128), tb, 0, stream>>>(
        xb, w1T + (size_t)l * NFF * ND, b1 + (size_t)l * NFF,
        nullptr, h1b, nullptr, nullptr, NM, NFF, ND);
    gemm_bt<EP_FF2, 64, 64, 2, 2, 64><<<dim3(NM / 64, ND / 64), tb128, 0, stream>>>(
        h1b, w2T + (size_t)l * ND * NFF, b2 + (size_t)l * ND,
        xf, xb, xf, nullptr, NM, ND, NFF);
  }
  ln_kernel<false><<<dim3(NM), tb, 0, stream>>>(xf, nullptr, lnf_g, lnf_b, nullptr, xlnb);
  gemm_bt<EP_HEAD, 256, 256, 4, 8, 32><<<dim3(NM / 256, (NV + 255) / 256), tb512, 0, stream>>>(
      xlnb, whT, b_head, out, nullptr, nullptr, nullptr, NM, NV, ND);
}

// Round 8
// 1131.920 us; speedup vs baseline: 1.0202x; 1.0202x over previous
//
#include <hip/hip_runtime.h>
#include <hip/hip_bf16.h>
#include <math.h>
#include <stdint.h>

#define NL 6
#define NB 2
#define ST 1024
#define ND 768
#define NH 12
#define HD 64
#define NFF 3072
#define NV 50257
#define ND3 2304
#define NM (NB * ST) // 2048

typedef short bf16x4 __attribute__((ext_vector_type(4)));
typedef short bf16x8 __attribute__((ext_vector_type(8)));
typedef float f32x4  __attribute__((ext_vector_type(4)));

typedef __attribute__((address_space(3))) void as3_void;
typedef __attribute__((address_space(1))) void as1_void;

// async global->LDS, 16B per lane; LDS dest is wave-uniform base + lane*16
__device__ __forceinline__ void async_copy16(const void* g, void* lds) {
  __builtin_amdgcn_global_load_lds((const as1_void*)(uintptr_t)g,
                                   (as3_void*)(uint32_t)(uintptr_t)lds,
                                   16, 0, 0);
}

__device__ __forceinline__ unsigned short f2bf(float f) {
  union { float f; uint32_t u; } v; v.f = f;
  return (unsigned short)((v.u + 0x7fffu + ((v.u >> 16) & 1u)) >> 16);
}

__device__ __forceinline__ bf16x8 frag16(const unsigned short* p) {
  return *(const bf16x8*)p;   // single ds_read_b128
}

// counted-vmcnt barrier: wait until only the NEXT tile(s)' own loads are in
// flight, then raw barrier (NO __syncthreads -> no vmcnt(0) drain).
template <int N>
__device__ __forceinline__ void wait_vm_barrier() {
  if constexpr (N == 8)      asm volatile("s_waitcnt vmcnt(8)\n\ts_barrier" ::: "memory");
  else if constexpr (N == 6) asm volatile("s_waitcnt vmcnt(6)\n\ts_barrier" ::: "memory");
  else if constexpr (N == 4) asm volatile("s_waitcnt vmcnt(4)\n\ts_barrier" ::: "memory");
  else                       asm volatile("s_waitcnt vmcnt(0)\n\ts_barrier" ::: "memory");
}
__device__ __forceinline__ void lgkm_barrier() {
  asm volatile("s_waitcnt lgkmcnt(0)\n\ts_barrier" ::: "memory");
}

#define MFMA(a, b, c) __builtin_amdgcn_mfma_f32_16x16x32_bf16((a), (b), (c), 0, 0, 0)

__device__ __forceinline__ float gelu_buggy(float x) {
  // faithful to ref: 0.5*x*(1+tanh(sqrt(2/pi) * 0.044715 * x^4))
  const float c = 0.7978845608028654f;
  float x2 = x * x;
  return 0.5f * x * (1.0f + tanhf(c * 0.044715f * x2 * x2));
}

enum { EP_QKV = 0, EP_PROJ, EP_FF1, EP_FF2, EP_HEAD };

// C[M,N] = A[M,K] @ BT[N,K]^T + bias, fused epilogue.
// BK-templated (32/64), NBUF-deep LDS ring (2 = classic dbuf, 3 = depth-2
// prefetch for latency-starved shapes), counted-vmcnt pipeline.
// Swizzle (bank-exact, 0 conflicts measured R7):
//   BK=64: rows 128B -> swz = row&7
//   BK=32: rows  64B -> swz = (row>>1)&3
// Same XOR on staging source and ds_read; identical slot->k map for A and
// B, so the K permutation cancels in the MFMA dot product.
// EP_QKV additionally scatters the V third into vT[b][h][d][t].
template <int EPI, int TM, int TN, int WN, int NW, int BK, int NBUF>
__global__ __launch_bounds__(NW * 64)
void gemm_bt(const unsigned short* __restrict__ A,
             const unsigned short* __restrict__ BT,
             const float* __restrict__ bias,
             float* __restrict__ Cf,
             unsigned short* __restrict__ Cb,
             const float* __restrict__ resid,
             unsigned short* __restrict__ vT,
             int M, int N, int K)
{
  constexpr int WM = NW / WN;
  constexpr int FM = TM / WM / 16;     // A frags per wave
  constexpr int FN = TN / WN / 16;     // B frags per wave
  constexpr int SL = BK / 8;           // 16B slots per row (8 or 4)
  constexpr int RS = (BK == 32) ? 1 : 0; // swizzle row shift (see header)
  constexpr int RPC = 1024 / (BK * 2); // rows per 1KB staging chunk
  constexpr int CA = TM / RPC / NW;    // A staging chunks per wave
  constexpr int CB = TN / RPC / NW;
  constexpr int LPT = CA + CB;         // loads per thread per K-step
  constexpr int KK = BK / 32;          // mfma k-slices per K-step
  constexpr int DEPTH = NBUF - 1;      // prefetch depth
  __shared__ __align__(16) unsigned short As[NBUF][TM * BK];
  __shared__ __align__(16) unsigned short Bs[NBUF][TN * BK];
  const int tid = threadIdx.x;
  const int w = tid >> 6, l = tid & 63;
  const int g = l >> 4, r = l & 15;
  const int wm = (w / WN) * (FM * 16);
  const int wn = (w % WN) * (FN * 16);

  // bijective XCD-aware swizzle (all grids here have nwg % 8 == 0)
  const int nbx = gridDim.x;
  const int nwg = nbx * gridDim.y;
  int bid = blockIdx.y * nbx + blockIdx.x;
  if ((nwg & 7) == 0) bid = (bid & 7) * (nwg >> 3) + (bid >> 3);
  const int m0 = (bid % nbx) * TM, n0 = (bid / nbx) * TN;

  // staging: chunk = RPC rows x BK*2 bytes; lanes-per-row = BK/8 (16B each).
  const int sr = l / (BK / 8);         // row within chunk
  const int se = ((l & (SL - 1)) ^ ((sr >> RS) & (SL - 1))) * 8;
  long aoff[CA];
  long boff[CB];
#pragma unroll
  for (int c = 0; c < CA; ++c) {
    const int arow = (w * CA + c) * RPC + sr;
    aoff[c] = (long)(m0 + arow) * K + se;
  }
#pragma unroll
  for (int c = 0; c < CB; ++c) {
    int brow = n0 + (w * CB + c) * RPC + sr;
    if (brow > N - 1) brow = N - 1;
    boff[c] = (long)brow * K + se;
  }

  f32x4 acc[FM][FN] = {};

  auto stage = [&](int t, int buf) {
    const long k0 = (long)t * BK;
#pragma unroll
    for (int c = 0; c < CA; ++c)
      async_copy16(A + aoff[c] + k0, &As[buf][(w * CA + c) * 512]);
#pragma unroll
    for (int c = 0; c < CB; ++c)
      async_copy16(BT + boff[c] + k0, &Bs[buf][(w * CB + c) * 512]);
  };

  auto compute = [&](int buf) {
#pragma unroll
    for (int kk = 0; kk < KK; ++kk) {
      bf16x8 af[FM], bf[FN];
#pragma unroll
      for (int mi = 0; mi < FM; ++mi)
        af[mi] = frag16(&As[buf][(wm + mi * 16 + r) * BK +
                                 (((kk * 4 + g) ^ ((r >> RS) & (SL - 1))) * 8)]);
#pragma unroll
      for (int ni = 0; ni < FN; ++ni)
        bf[ni] = frag16(&Bs[buf][(wn + ni * 16 + r) * BK +
                                 (((kk * 4 + g) ^ ((r >> RS) & (SL - 1))) * 8)]);
      __builtin_amdgcn_s_setprio(1);
#pragma unroll
      for (int mi = 0; mi < FM; ++mi)
#pragma unroll
        for (int ni = 0; ni < FN; ++ni)
          acc[mi][ni] = MFMA(af[mi], bf[ni], acc[mi][ni]);
      __builtin_amdgcn_s_setprio(0);
    }
  };

  const int nt = K / BK;
  // prologue: fill DEPTH buffers
  stage(0, 0);
  if (DEPTH == 2) stage(1, 1);
  int cur = 0, nxt = DEPTH;            // nxt = buffer for tile t+DEPTH
  for (int t = 0; t < nt; ++t) {
    const bool have_next = (t + DEPTH) < nt;
    if (have_next) stage(t + DEPTH, nxt);
    // wait for tile t: outstanding = own loads of the tiles after t
    if (have_next && DEPTH == 2)       wait_vm_barrier<2 * LPT>();
    else if (have_next || (DEPTH == 2 && t + 1 < nt)) wait_vm_barrier<LPT>();
    else                               wait_vm_barrier<0>();
    compute(cur);
    if (t + 1 < nt) lgkm_barrier();    // readers done before buf reuse
    cur = (cur + 1 == NBUF) ? 0 : cur + 1;
    nxt = (nxt + 1 == NBUF) ? 0 : nxt + 1;
  }

#pragma unroll
  for (int mi = 0; mi < FM; ++mi) {
#pragma unroll
    for (int ni = 0; ni < FN; ++ni) {
      const int col = n0 + wn + ni * 16 + r;
      if (EPI == EP_HEAD && col >= N) continue;
      const float bb = bias[col];
      if (EPI == EP_QKV && col >= 2 * ND) {
        // V third -> vT[b][h][d][t] (bf16), 4 consecutive t per lane
        const int hv = (col - 2 * ND) >> 6, d = (col - 2 * ND) & 63;
        short4 vv;
#pragma unroll
        for (int q = 0; q < 4; ++q)
          vv[q] = (short)f2bf(acc[mi][ni][q] + bb);
        const int row = m0 + wm + mi * 16 + g * 4;
        const int bb_ = row >> 10, t4 = row & 1023;
        *(short4*)&vT[(((long)bb_ * NH + hv) * HD + d) * ST + t4] = vv;
        continue;
      }
#pragma unroll
      for (int q = 0; q < 4; ++q) {
        const int row = m0 + wm + mi * 16 + g * 4 + q;
        float v = acc[mi][ni][q] + bb;
        if constexpr (EPI == EP_QKV) {
          Cb[(long)row * N + col] = f2bf(v);
        } else if constexpr (EPI == EP_PROJ) {
          Cf[(long)row * N + col] = v;
        } else if constexpr (EPI == EP_FF1) {
          Cb[(long)row * N + col] = f2bf(gelu_buggy(v));
        } else if constexpr (EPI == EP_FF2) {
          float o = v + resid[(long)row * N + col];
          Cf[(long)row * N + col] = o;
          Cb[(long)row * N + col] = f2bf(o);
        } else { // EP_HEAD
          Cf[(long)row * N + col] = v;
        }
      }
    }
  }
}

// Flash attention, no mask. Block = 4 waves, one (b,h) x 64 q-rows.
// Each wave owns 16 q-rows. LDS stride 72 avoids D=64 bank conflicts.
// V^T comes pre-transposed from the QKV epilogue (vT[b][h][d][t]).
__global__ __launch_bounds__(256)
void attn_kernel(const unsigned short* __restrict__ qkv,
                 const unsigned short* __restrict__ vT,
                 unsigned short* __restrict__ y)
{
  constexpr int LS = 72;
  __shared__ __align__(16) unsigned short Qs[64 * LS];
  __shared__ __align__(16) unsigned short Ks[64 * LS];
  __shared__ __align__(16) unsigned short Vt[64 * LS];
  __shared__ __align__(16) unsigned short Ps[64 * LS];
  const int tid = threadIdx.x;
  const int w = tid >> 6, l = tid & 63;
  const int g = l >> 4, r = l & 15;
  const int q0 = blockIdx.x * 64;
  const int b = blockIdx.y / NH, h = blockIdx.y % NH;
  const long rb = (long)b * ST;
  const long vbase = ((long)b * NH + h) * HD * ST;
  const int srow = tid >> 3, sc8 = (tid & 7) * 8;

  // stage Q tile [64 rows][64 dims]
#pragma unroll
  for (int p = 0; p < 2; ++p) {
    const int row = p * 32 + srow;
    bf16x8 v = *(const bf16x8*)&qkv[(rb + q0 + row) * ND3 + h * HD + sc8];
    *(bf16x8*)&Qs[row * LS + sc8] = v;
  }
  __syncthreads();
  // Q fragments hoisted out of the KV loop (Qs is never overwritten)
  bf16x8 aq[2];
#pragma unroll
  for (int kk = 0; kk < 2; ++kk)
    aq[kk] = *(const bf16x8*)&Qs[(w * 16 + r) * LS + kk * 32 + g * 8];

  float m_run[4] = {-1e30f, -1e30f, -1e30f, -1e30f};
  float l_run[4] = {0.f, 0.f, 0.f, 0.f};
  f32x4 acc_o[4] = {};

  for (int kt = 0; kt < ST / 64; ++kt) {
#pragma unroll
    for (int p = 0; p < 2; ++p) {
      const int row = p * 32 + srow;
      *(bf16x8*)&Ks[row * LS + sc8] =
          *(const bf16x8*)&qkv[(rb + kt * 64 + row) * ND3 + ND + h * HD + sc8];
      *(bf16x8*)&Vt[row * LS + sc8] =
          *(const bf16x8*)&vT[vbase + (long)row * ST + kt * 64 + sc8];
    }
    __syncthreads();

    // S = Q K^T for this wave's 16 q-rows
    f32x4 s_acc[4] = {};
#pragma unroll
    for (int kk = 0; kk < 2; ++kk) {
#pragma unroll
      for (int ni = 0; ni < 4; ++ni) {
        bf16x8 bk = *(const bf16x8*)&Ks[(ni * 16 + r) * LS + kk * 32 + g * 8];
        s_acc[ni] = MFMA(aq[kk], bk, s_acc[ni]);
      }
    }

    // online softmax; lane owns rows g*4+q at cols ni*16+r
    float mloc[4];
#pragma unroll
    for (int q = 0; q < 4; ++q) {
      float mx = fmaxf(fmaxf(s_acc[0][q], s_acc[1][q]), fmaxf(s_acc[2][q], s_acc[3][q]));
      mloc[q] = mx * 0.125f;
    }
#pragma unroll
    for (int mask = 1; mask < 16; mask <<= 1)
#pragma unroll
      for (int q = 0; q < 4; ++q)
        mloc[q] = fmaxf(mloc[q], __shfl_xor(mloc[q], mask, 64));

    float alpha[4], psum[4] = {0.f, 0.f, 0.f, 0.f};
#pragma unroll
    for (int q = 0; q < 4; ++q) {
      const float mn = fmaxf(m_run[q], mloc[q]);
      alpha[q] = __expf(m_run[q] - mn);
      m_run[q] = mn;
    }
#pragma unroll
    for (int ni = 0; ni < 4; ++ni)
#pragma unroll
      for (int q = 0; q < 4; ++q) {
        const float p = __expf(s_acc[ni][q] * 0.125f - m_run[q]);
        psum[q] += p;
        Ps[(w * 16 + g * 4 + q) * LS + ni * 16 + r] = f2bf(p);
      }
#pragma unroll
    for (int mask = 1; mask < 16; mask <<= 1)
#pragma unroll
      for (int q = 0; q < 4; ++q) psum[q] += __shfl_xor(psum[q], mask, 64);
#pragma unroll
    for (int q = 0; q < 4; ++q) l_run[q] = l_run[q] * alpha[q] + psum[q];
#pragma unroll
    for (int ni = 0; ni < 4; ++ni)
#pragma unroll
      for (int q = 0; q < 4; ++q) acc_o[ni][q] *= alpha[q];

    // wave-local P writes must land before reading as MFMA A-operand
    asm volatile("s_waitcnt lgkmcnt(0)" ::: "memory");
    __builtin_amdgcn_sched_barrier(0);

    // O += P @ V
#pragma unroll
    for (int kk = 0; kk < 2; ++kk) {
      bf16x8 ap = *(const bf16x8*)&Ps[(w * 16 + r) * LS + kk * 32 + g * 8];
#pragma unroll
      for (int ni = 0; ni < 4; ++ni) {
        bf16x8 bv = *(const bf16x8*)&Vt[(ni * 16 + r) * LS + kk * 32 + g * 8];
        acc_o[ni] = MFMA(ap, bv, acc_o[ni]);
      }
    }
    __syncthreads();  // all reads of Ks/Vt done before next stage
  }

#pragma unroll
  for (int ni = 0; ni < 4; ++ni)
#pragma unroll
    for (int q = 0; q < 4; ++q) {
      const int row = q0 + w * 16 + g * 4 + q;
      const int col = h * HD + ni * 16 + r;
      y[(rb + row) * ND + col] = f2bf(acc_o[ni][q] / l_run[q]);
    }
}

// LayerNorm over D=768 (+optional residual add); writes fp32 and/or bf16.
template <bool RESID>
__global__ __launch_bounds__(256)
void ln_kernel(const float* __restrict__ in, const float* __restrict__ resid,
               const float* __restrict__ gamma, const float* __restrict__ beta,
               float* __restrict__ out_f, unsigned short* __restrict__ out_b)
{
  __shared__ float wred[8];
  const int row = blockIdx.x, tid = threadIdx.x;
  float v[3];
#pragma unroll
  for (int j = 0; j < 3; ++j) v[j] = in[(long)row * ND + tid + j * 256];
  float s = v[0] + v[1] + v[2];
#pragma unroll
  for (int m = 1; m < 64; m <<= 1) s += __shfl_xor(s, m, 64);
  if ((tid & 63) == 0) wred[tid >> 6] = s;
  __syncthreads();
  const float mean = (wred[0] + wred[1] + wred[2] + wred[3]) * (1.0f / ND);
  float d[3];
#pragma unroll
  for (int j = 0; j < 3; ++j) d[j] = v[j] - mean;
  float s2 = d[0] * d[0] + d[1] * d[1] + d[2] * d[2];
#pragma unroll
  for (int m = 1; m < 64; m <<= 1) s2 += __shfl_xor(s2, m, 64);
  if ((tid & 63) == 0) wred[4 + (tid >> 6)] = s2;
  __syncthreads();
  const float var = (wred[4] + wred[5] + wred[6] + wred[7]) * (1.0f / ND);
  const float rstd = rsqrtf(var + 1e-5f);
#pragma unroll
  for (int j = 0; j < 3; ++j) {
    const int c = tid + j * 256;
    float o = d[j] * rstd * gamma[c] + beta[c];
    if (RESID) o += resid[(long)row * ND + c];
    if (out_f) out_f[(long)row * ND + c] = o;
    if (out_b) out_b[(long)row * ND + c] = f2bf(o);
  }
}

__global__ __launch_bounds__(256)
void embed_kernel(const int* __restrict__ ids, const float* __restrict__ wte,
                  const float* __restrict__ wpe, float* __restrict__ x,
                  unsigned short* __restrict__ xb)
{
  const int t = blockIdx.x, tid = threadIdx.x;
  const int tok = ids[t];
  const int pos = t & (ST - 1);
#pragma unroll
  for (int j = 0; j < 3; ++j) {
    const int c = tid + j * 256;
    const float v = wte[(long)tok * ND + c] + wpe[(long)pos * ND + c];
    x[(long)t * ND + c] = v;
    xb[(long)t * ND + c] = f2bf(v);
  }
}

// fp32 [z][R][C] -> bf16 [z][C][R], 64(R)x32(C) tiles, coalesced both sides.
__global__ __launch_bounds__(256)
void transpose_bf16(const float* __restrict__ in, unsigned short* __restrict__ out,
                    int R, int C)
{
  __shared__ float tile[64][33];
  const long z = (long)blockIdx.z * R * C;
  const int c0 = blockIdx.x * 32, r0 = blockIdx.y * 64;
  const int tx = threadIdx.x & 31, ty = threadIdx.x >> 5;   // read indexing
#pragma unroll
  for (int j = 0; j < 8; ++j) {
    const int rr = r0 + j * 8 + ty, cc = c0 + tx;
    if (cc < C) tile[j * 8 + ty][tx] = in[z + (long)rr * C + cc];
  }
  __syncthreads();
  const int rx = threadIdx.x & 63, cy = threadIdx.x >> 6;   // write indexing
#pragma unroll
  for (int j = 0; j < 8; ++j) {
    const int cc = c0 + j * 4 + cy;
    if (cc < C) out[z + (long)cc * R + r0 + rx] = f2bf(tile[rx][j * 4 + cy]);
  }
}

extern "C" void kernel_launch(void* const* d_in, const int* in_sizes, int n_in,
                              void* d_out, int out_size, void* d_ws, size_t ws_size,
                              hipStream_t stream)
{
  const int*   ids    = (const int*)d_in[0];
  const float* wte    = (const float*)d_in[1];
  const float* wpe    = (const float*)d_in[2];
  const float* W_qkv  = (const float*)d_in[3];
  const float* b_qkv  = (const float*)d_in[4];
  const float* W_o    = (const float*)d_in[5];
  const float* b_o    = (const float*)d_in[6];
  const float* ln1_g  = (const float*)d_in[7];
  const float* ln1_b  = (const float*)d_in[8];
  const float* W1     = (const float*)d_in[9];
  const float* b1     = (const float*)d_in[10];
  const float* W2     = (const float*)d_in[11];
  const float* b2     = (const float*)d_in[12];
  const float* lnf_g  = (const float*)d_in[13];
  const float* lnf_b  = (const float*)d_in[14];
  const float* W_head = (const float*)d_in[15];
  const float* b_head = (const float*)d_in[16];
  float* out = (float*)d_out;
  (void)in_sizes; (void)n_in; (void)out_size; (void)ws_size;

  char* ws = (char*)d_ws;
  size_t off = 0;
  auto alloc = [&](size_t bytes) -> void* {
    void* p = (void*)(ws + off);
    off = (off + bytes + 255) & ~(size_t)255;
    return p;
  };
  unsigned short* wqkvT = (unsigned short*)alloc((size_t)NL * ND3 * ND * 2);
  unsigned short* woT   = (unsigned short*)alloc((size_t)NL * ND * ND * 2);
  unsigned short* w1T   = (unsigned short*)alloc((size_t)NL * NFF * ND * 2);
  unsigned short* w2T   = (unsigned short*)alloc((size_t)NL * ND * NFF * 2);
  unsigned short* whT   = (unsigned short*)alloc((size_t)NV * ND * 2);
  float*          xf    = (float*)alloc((size_t)NM * ND * 4);
  unsigned short* xb    = (unsigned short*)alloc((size_t)NM * ND * 2);
  unsigned short* qkvb  = (unsigned short*)alloc((size_t)NM * ND3 * 2);
  unsigned short* yb    = (unsigned short*)alloc((size_t)NM * ND * 2);
  float*          aof   = (float*)alloc((size_t)NM * ND * 4);
  unsigned short* h1b   = (unsigned short*)alloc((size_t)NM * NFF * 2);
  unsigned short* xlnb  = (unsigned short*)alloc((size_t)NM * ND * 2);
  unsigned short* vtb   = (unsigned short*)alloc((size_t)NB * NH * HD * ST * 2);

  dim3 tb(256);
  dim3 tb128(128);
  dim3 tb512(512);
  // weight convert+transpose (fp32 [K][N] -> bf16 [N][K])
  transpose_bf16<<<dim3(ND3 / 32, ND / 64, NL), tb, 0, stream>>>(W_qkv, wqkvT, ND, ND3);
  transpose_bf16<<<dim3(ND / 32, ND / 64, NL), tb, 0, stream>>>(W_o, woT, ND, ND);
  transpose_bf16<<<dim3(NFF / 32, ND / 64, NL), tb, 0, stream>>>(W1, w1T, ND, NFF);
  transpose_bf16<<<dim3(ND / 32, NFF / 64, NL), tb, 0, stream>>>(W2, w2T, NFF, ND);
  transpose_bf16<<<dim3((NV + 31) / 32, ND / 64, 1), tb, 0, stream>>>(W_head, whT, ND, NV);

  embed_kernel<<<dim3(NM), tb, 0, stream>>>(ids, wte, wpe, xf, xb);

  for (int l = 0; l < NL; ++l) {
    gemm_bt<EP_QKV, 128, 64, 2, 4, 64, 2><<<dim3(NM / 128, ND3 / 64), tb, 0, stream>>>(
        xb, wqkvT + (size_t)l * ND3 * ND, b_qkv + (size_t)l * ND3,
        nullptr, qkvb, nullptr, vtb, NM, ND3, ND);
    attn_kernel<<<dim3(ST / 64, NB * NH), tb, 0, stream>>>(qkvb, vtb, yb);
    gemm_bt<EP_PROJ, 64, 64, 2, 2, 64, 2><<<dim3(NM / 64, ND / 64), tb128, 0, stream>>>(
        yb, woT + (size_t)l * ND * ND, b_o + (size_t)l * ND,
        aof, nullptr, nullptr, nullptr, NM, ND, ND);
    ln_kernel<true><<<dim3(NM), tb, 0, stream>>>(
        aof, xf, ln1_g + (size_t)l * ND, ln1_b + (size_t)l * ND, xf, xb);
    gemm_bt<EP_FF1, 128, 64, 2, 4, 64, 2><<<dim3(NM / 128, NFF / 64), tb, 0, stream>>>(
        xb, w1T + (size_t)l * NFF * ND, b1 + (size_t)l * NFF,
        nullptr, h1b, nullptr, nullptr, NM, NFF, ND);
    gemm_bt<EP_FF2, 64, 64, 2, 2, 64, 2><<<dim3(NM / 64, ND / 64), tb128, 0, stream>>>(
        h1b, w2T + (size_t)l * ND * NFF, b2 + (size_t)l * ND,
        xf, xb, xf, nullptr, NM, ND, NFF);
  }
  ln_kernel<false><<<dim3(NM), tb, 0, stream>>>(xf, nullptr, lnf_g, lnf_b, nullptr, xlnb);
  gemm_bt<EP_HEAD, 256, 256, 4, 8, 32, 3><<<dim3(NM / 256, (NV + 255) / 256), tb512, 0, stream>>>(
      xlnb, whT, b_head, out, nullptr, nullptr, nullptr, NM, NV, ND);
}

// Round 9
// 1104.592 us; speedup vs baseline: 1.0454x; 1.0247x over previous
//
#include <hip/hip_runtime.h>
#include <hip/hip_bf16.h>
#include <math.h>
#include <stdint.h>

#define NL 6
#define NB 2
#define ST 1024
#define ND 768
#define NH 12
#define HD 64
#define NFF 3072
#define NV 50257
#define ND3 2304
#define NM (NB * ST) // 2048

typedef short bf16x4 __attribute__((ext_vector_type(4)));
typedef short bf16x8 __attribute__((ext_vector_type(8)));
typedef float f32x4  __attribute__((ext_vector_type(4)));

typedef __attribute__((address_space(3))) void as3_void;
typedef __attribute__((address_space(1))) void as1_void;

// async global->LDS, 16B per lane; LDS dest is wave-uniform base + lane*16
__device__ __forceinline__ void async_copy16(const void* g, void* lds) {
  __builtin_amdgcn_global_load_lds((const as1_void*)(uintptr_t)g,
                                   (as3_void*)(uint32_t)(uintptr_t)lds,
                                   16, 0, 0);
}

__device__ __forceinline__ unsigned short f2bf(float f) {
  union { float f; uint32_t u; } v; v.f = f;
  return (unsigned short)((v.u + 0x7fffu + ((v.u >> 16) & 1u)) >> 16);
}

__device__ __forceinline__ bf16x8 frag16(const unsigned short* p) {
  return *(const bf16x8*)p;   // single ds_read_b128
}

// counted-vmcnt barrier: wait until only the NEXT tile(s)' own loads are in
// flight, then raw barrier (NO __syncthreads -> no vmcnt(0) drain).
template <int N>
__device__ __forceinline__ void wait_vm_barrier() {
  if constexpr (N == 8)      asm volatile("s_waitcnt vmcnt(8)\n\ts_barrier" ::: "memory");
  else if constexpr (N == 6) asm volatile("s_waitcnt vmcnt(6)\n\ts_barrier" ::: "memory");
  else if constexpr (N == 5) asm volatile("s_waitcnt vmcnt(5)\n\ts_barrier" ::: "memory");
  else if constexpr (N == 4) asm volatile("s_waitcnt vmcnt(4)\n\ts_barrier" ::: "memory");
  else                       asm volatile("s_waitcnt vmcnt(0)\n\ts_barrier" ::: "memory");
}
__device__ __forceinline__ void lgkm_barrier() {
  asm volatile("s_waitcnt lgkmcnt(0)\n\ts_barrier" ::: "memory");
}

#define MFMA(a, b, c) __builtin_amdgcn_mfma_f32_16x16x32_bf16((a), (b), (c), 0, 0, 0)

__device__ __forceinline__ float gelu_buggy(float x) {
  // faithful to ref: 0.5*x*(1+tanh(sqrt(2/pi) * 0.044715 * x^4))
  const float c = 0.7978845608028654f;
  float x2 = x * x;
  return 0.5f * x * (1.0f + tanhf(c * 0.044715f * x2 * x2));
}

enum { EP_QKV = 0, EP_PROJ, EP_FF1, EP_FF2, EP_HEAD };

// ---------------- layer GEMM (R8-verified 2-phase, counted vmcnt) ----------
template <int EPI, int TM, int TN, int WN, int NW, int BK, int NBUF>
__global__ __launch_bounds__(NW * 64)
void gemm_bt(const unsigned short* __restrict__ A,
             const unsigned short* __restrict__ BT,
             const float* __restrict__ bias,
             float* __restrict__ Cf,
             unsigned short* __restrict__ Cb,
             const float* __restrict__ resid,
             unsigned short* __restrict__ vT,
             int M, int N, int K)
{
  constexpr int WM = NW / WN;
  constexpr int FM = TM / WM / 16;
  constexpr int FN = TN / WN / 16;
  constexpr int SL = BK / 8;
  constexpr int RS = (BK == 32) ? 1 : 0;
  constexpr int RPC = 1024 / (BK * 2);
  constexpr int CA = TM / RPC / NW;
  constexpr int CB = TN / RPC / NW;
  constexpr int LPT = CA + CB;
  constexpr int KK = BK / 32;
  constexpr int DEPTH = NBUF - 1;
  __shared__ __align__(16) unsigned short As[NBUF][TM * BK];
  __shared__ __align__(16) unsigned short Bs[NBUF][TN * BK];
  const int tid = threadIdx.x;
  const int w = tid >> 6, l = tid & 63;
  const int g = l >> 4, r = l & 15;
  const int wm = (w / WN) * (FM * 16);
  const int wn = (w % WN) * (FN * 16);

  const int nbx = gridDim.x;
  const int nwg = nbx * gridDim.y;
  int bid = blockIdx.y * nbx + blockIdx.x;
  if ((nwg & 7) == 0) bid = (bid & 7) * (nwg >> 3) + (bid >> 3);
  const int m0 = (bid % nbx) * TM, n0 = (bid / nbx) * TN;

  const int sr = l / (BK / 8);
  const int se = ((l & (SL - 1)) ^ ((sr >> RS) & (SL - 1))) * 8;
  long aoff[CA];
  long boff[CB];
#pragma unroll
  for (int c = 0; c < CA; ++c) {
    const int arow = (w * CA + c) * RPC + sr;
    aoff[c] = (long)(m0 + arow) * K + se;
  }
#pragma unroll
  for (int c = 0; c < CB; ++c) {
    int brow = n0 + (w * CB + c) * RPC + sr;
    if (brow > N - 1) brow = N - 1;
    boff[c] = (long)brow * K + se;
  }

  f32x4 acc[FM][FN] = {};

  auto stage = [&](int t, int buf) {
    const long k0 = (long)t * BK;
#pragma unroll
    for (int c = 0; c < CA; ++c)
      async_copy16(A + aoff[c] + k0, &As[buf][(w * CA + c) * 512]);
#pragma unroll
    for (int c = 0; c < CB; ++c)
      async_copy16(BT + boff[c] + k0, &Bs[buf][(w * CB + c) * 512]);
  };

  auto compute = [&](int buf) {
#pragma unroll
    for (int kk = 0; kk < KK; ++kk) {
      bf16x8 af[FM], bf[FN];
#pragma unroll
      for (int mi = 0; mi < FM; ++mi)
        af[mi] = frag16(&As[buf][(wm + mi * 16 + r) * BK +
                                 (((kk * 4 + g) ^ ((r >> RS) & (SL - 1))) * 8)]);
#pragma unroll
      for (int ni = 0; ni < FN; ++ni)
        bf[ni] = frag16(&Bs[buf][(wn + ni * 16 + r) * BK +
                                 (((kk * 4 + g) ^ ((r >> RS) & (SL - 1))) * 8)]);
      __builtin_amdgcn_s_setprio(1);
#pragma unroll
      for (int mi = 0; mi < FM; ++mi)
#pragma unroll
        for (int ni = 0; ni < FN; ++ni)
          acc[mi][ni] = MFMA(af[mi], bf[ni], acc[mi][ni]);
      __builtin_amdgcn_s_setprio(0);
    }
  };

  const int nt = K / BK;
  stage(0, 0);
  if (DEPTH == 2) stage(1, 1);
  int cur = 0, nxt = DEPTH;
  for (int t = 0; t < nt; ++t) {
    const bool have_next = (t + DEPTH) < nt;
    if (have_next) stage(t + DEPTH, nxt);
    if (have_next && DEPTH == 2)       wait_vm_barrier<2 * LPT>();
    else if (have_next || (DEPTH == 2 && t + 1 < nt)) wait_vm_barrier<LPT>();
    else                               wait_vm_barrier<0>();
    compute(cur);
    if (t + 1 < nt) lgkm_barrier();
    cur = (cur + 1 == NBUF) ? 0 : cur + 1;
    nxt = (nxt + 1 == NBUF) ? 0 : nxt + 1;
  }

#pragma unroll
  for (int mi = 0; mi < FM; ++mi) {
#pragma unroll
    for (int ni = 0; ni < FN; ++ni) {
      const int col = n0 + wn + ni * 16 + r;
      const float bb = bias[col];
      if (EPI == EP_QKV && col >= 2 * ND) {
        const int hv = (col - 2 * ND) >> 6, d = (col - 2 * ND) & 63;
        short4 vv;
#pragma unroll
        for (int q = 0; q < 4; ++q)
          vv[q] = (short)f2bf(acc[mi][ni][q] + bb);
        const int row = m0 + wm + mi * 16 + g * 4;
        const int bb_ = row >> 10, t4 = row & 1023;
        *(short4*)&vT[(((long)bb_ * NH + hv) * HD + d) * ST + t4] = vv;
        continue;
      }
#pragma unroll
      for (int q = 0; q < 4; ++q) {
        const int row = m0 + wm + mi * 16 + g * 4 + q;
        float v = acc[mi][ni][q] + bb;
        if constexpr (EPI == EP_QKV) {
          Cb[(long)row * N + col] = f2bf(v);
        } else if constexpr (EPI == EP_PROJ) {
          Cf[(long)row * N + col] = v;
        } else if constexpr (EPI == EP_FF1) {
          Cb[(long)row * N + col] = f2bf(gelu_buggy(v));
        } else if constexpr (EPI == EP_FF2) {
          float o = v + resid[(long)row * N + col];
          Cf[(long)row * N + col] = o;
          Cb[(long)row * N + col] = f2bf(o);
        }
      }
    }
  }
}

// ---------------- head GEMM: 8-phase m201-template port --------------------
// BM=BN=256, BK=64, 8 waves (2M x 4N), 512 thr, 128KB LDS (2 dbuf).
// Per-wave C = 128x64 = 8mi x 4ni frags; 16 MFMA/phase (2mi x 4ni x 2kk);
// B frags register-cached per K-tile (12 ds_reads at tile-open, else 4).
// Staging units: A-stripe q (64 rows: [32q,32q+32) in each half, 1 load/thr),
// B-half h (128 rows, 2 loads/thr). Unit staged exactly one phase after its
// region's last reader passed that phase's closing barrier:
//   P1: A3(T+1),B0(T+1) | P2: A0(T+2),B1(T+1) | P3: A1(T+2) | P4: A2(T+2)
//   P5: A3(T+2),B0(T+2) | P6: A0(T+3),B1(T+2) | P7: A1(T+3) | P8: A2(T+3)
// (A-unit issued before B-unit within a phase so B1 is each tile's last load.)
// Per-wave issue ledger -> counted vmcnt: after B1(T) land, 5 newer loads are
// in flight at steady P1/P5 -> vmcnt(5). Iter0: vmcnt(8)@P1, vmcnt(6)@P5
// (prologue stages tiles 0,1 = 16 loads). Last iter: vmcnt(0)@P5 only.
__global__ __launch_bounds__(512, 2)
void gemm_head_8ph(const unsigned short* __restrict__ A,
                   const unsigned short* __restrict__ BT,
                   const float* __restrict__ bias,
                   float* __restrict__ Cf,
                   int M, int N, int K)
{
  __shared__ __align__(16) unsigned short As[2][256 * 64];
  __shared__ __align__(16) unsigned short Bs[2][256 * 64];
  const int tid = threadIdx.x;
  const int w = tid >> 6, l = tid & 63;
  const int g = l >> 4, r = l & 15;
  const int wm = (w >> 2) * 128;       // waves 0-3 -> rows 0-127, 4-7 -> 128-255
  const int wn = (w & 3) * 64;

  const int nbx = gridDim.x;
  const int nwg = nbx * gridDim.y;
  int bid = blockIdx.y * nbx + blockIdx.x;
  bid = (bid & 7) * (nwg >> 3) + (bid >> 3);   // nwg % 8 == 0 (8 x 197)
  const int m0 = (bid % nbx) * 256, n0 = (bid / nbx) * 256;

  const int sr = l >> 3;               // lane row-in-8
  const int se = ((l & 7) ^ sr) * 8;   // pre-swizzled source slot (elements)
  const int a_base0 = (w < 4 ? 0 : 128) + (w & 3) * 8;  // + q*32

  auto stageA = [&](int tt, int q) {   // 1 load/thread
    const int row = a_base0 + q * 32;  // wave-uniform LDS row base
    async_copy16(A + (long)(m0 + row + sr) * K + tt * 64 + se,
                 &As[tt & 1][row * 64]);
  };
  auto stageB = [&](int tt, int h) {   // 2 loads/thread
#pragma unroll
    for (int c = 0; c < 2; ++c) {
      const int row = h * 128 + w * 16 + c * 8;
      int brow = n0 + row + sr; if (brow > N - 1) brow = N - 1;
      async_copy16(BT + (long)brow * K + tt * 64 + se,
                   &Bs[tt & 1][row * 64]);
    }
  };
  auto ldA = [&](int buf, int mi, int kk) -> bf16x8 {
    const int row = wm + mi * 16 + r;
    return frag16(&As[buf][row * 64 + (((kk * 4 + g) ^ (r & 7)) * 8)]);
  };
  auto ldB = [&](int buf, int ni, int kk) -> bf16x8 {
    const int row = wn + ni * 16 + r;
    return frag16(&Bs[buf][row * 64 + (((kk * 4 + g) ^ (r & 7)) * 8)]);
  };

  f32x4 acc[8][4] = {};
  bf16x8 bfr[4][2];

#define DO_PHASE(buf, p, first)                                           \
  do {                                                                    \
    bf16x8 af[2][2];                                                      \
    _Pragma("unroll")                                                     \
    for (int i_ = 0; i_ < 2; ++i_)                                        \
      _Pragma("unroll")                                                   \
      for (int k_ = 0; k_ < 2; ++k_)                                      \
        af[i_][k_] = ldA(buf, 2 * (p) + i_, k_);                          \
    if (first) {                                                          \
      _Pragma("unroll")                                                   \
      for (int n_ = 0; n_ < 4; ++n_)                                      \
        _Pragma("unroll")                                                 \
        for (int k_ = 0; k_ < 2; ++k_)                                    \
          bfr[n_][k_] = ldB(buf, n_, k_);                                 \
    }                                                                     \
    asm volatile("s_barrier" ::: "memory");                               \
    asm volatile("s_waitcnt lgkmcnt(0)" ::: "memory");                    \
    __builtin_amdgcn_sched_barrier(0);                                    \
    __builtin_amdgcn_s_setprio(1);                                        \
    _Pragma("unroll")                                                     \
    for (int i_ = 0; i_ < 2; ++i_)                                        \
      _Pragma("unroll")                                                   \
      for (int n_ = 0; n_ < 4; ++n_)                                      \
        _Pragma("unroll")                                                 \
        for (int k_ = 0; k_ < 2; ++k_)                                    \
          acc[2 * (p) + i_][n_] =                                         \
              MFMA(af[i_][k_], bfr[n_][k_], acc[2 * (p) + i_][n_]);       \
    __builtin_amdgcn_s_setprio(0);                                        \
    asm volatile("s_barrier" ::: "memory");                               \
  } while (0)

  const int nt = K >> 6;               // 12
  const int niter = nt >> 1;           // 6

  // prologue: tiles 0 and 1 fully staged (8 + 8 loads per thread)
#pragma unroll
  for (int q = 0; q < 4; ++q) stageA(0, q);
  stageB(0, 0); stageB(0, 1);
#pragma unroll
  for (int q = 0; q < 4; ++q) stageA(1, q);
  stageB(1, 0); stageB(1, 1);

  for (int it = 0; it < niter; ++it) {
    const int T = 2 * it;
    // P1
    if (it > 0) { stageA(T + 1, 3); stageB(T + 1, 0); }
    if (it == 0) wait_vm_barrier<8>(); else wait_vm_barrier<5>();
    DO_PHASE(0, 0, true);
    // P2
    if (T + 2 < nt) stageA(T + 2, 0);
    if (it > 0) stageB(T + 1, 1);
    DO_PHASE(0, 1, false);
    // P3
    if (T + 2 < nt) stageA(T + 2, 1);
    DO_PHASE(0, 2, false);
    // P4
    if (T + 2 < nt) stageA(T + 2, 2);
    DO_PHASE(0, 3, false);
    // P5
    if (T + 2 < nt) { stageA(T + 2, 3); stageB(T + 2, 0); }
    if (it == 0) wait_vm_barrier<6>();
    else if (it == niter - 1) wait_vm_barrier<0>();
    else wait_vm_barrier<5>();
    DO_PHASE(1, 0, true);
    // P6
    if (T + 3 < nt) stageA(T + 3, 0);
    if (T + 2 < nt) stageB(T + 2, 1);
    DO_PHASE(1, 1, false);
    // P7
    if (T + 3 < nt) stageA(T + 3, 1);
    DO_PHASE(1, 2, false);
    // P8
    if (T + 3 < nt) stageA(T + 3, 2);
    DO_PHASE(1, 3, false);
  }
#undef DO_PHASE

#pragma unroll
  for (int mi = 0; mi < 8; ++mi) {
#pragma unroll
    for (int ni = 0; ni < 4; ++ni) {
      const int col = n0 + wn + ni * 16 + r;
      if (col >= N) continue;
      const float bb = bias[col];
#pragma unroll
      for (int q = 0; q < 4; ++q) {
        const int row = m0 + wm + mi * 16 + g * 4 + q;
        Cf[(long)row * N + col] = acc[mi][ni][q] + bb;
      }
    }
  }
}

// Flash attention, no mask. Block = 4 waves, one (b,h) x 64 q-rows.
__global__ __launch_bounds__(256)
void attn_kernel(const unsigned short* __restrict__ qkv,
                 const unsigned short* __restrict__ vT,
                 unsigned short* __restrict__ y)
{
  constexpr int LS = 72;
  __shared__ __align__(16) unsigned short Qs[64 * LS];
  __shared__ __align__(16) unsigned short Ks[64 * LS];
  __shared__ __align__(16) unsigned short Vt[64 * LS];
  __shared__ __align__(16) unsigned short Ps[64 * LS];
  const int tid = threadIdx.x;
  const int w = tid >> 6, l = tid & 63;
  const int g = l >> 4, r = l & 15;
  const int q0 = blockIdx.x * 64;
  const int b = blockIdx.y / NH, h = blockIdx.y % NH;
  const long rb = (long)b * ST;
  const long vbase = ((long)b * NH + h) * HD * ST;
  const int srow = tid >> 3, sc8 = (tid & 7) * 8;

#pragma unroll
  for (int p = 0; p < 2; ++p) {
    const int row = p * 32 + srow;
    bf16x8 v = *(const bf16x8*)&qkv[(rb + q0 + row) * ND3 + h * HD + sc8];
    *(bf16x8*)&Qs[row * LS + sc8] = v;
  }
  __syncthreads();
  bf16x8 aq[2];
#pragma unroll
  for (int kk = 0; kk < 2; ++kk)
    aq[kk] = *(const bf16x8*)&Qs[(w * 16 + r) * LS + kk * 32 + g * 8];

  float m_run[4] = {-1e30f, -1e30f, -1e30f, -1e30f};
  float l_run[4] = {0.f, 0.f, 0.f, 0.f};
  f32x4 acc_o[4] = {};

  for (int kt = 0; kt < ST / 64; ++kt) {
#pragma unroll
    for (int p = 0; p < 2; ++p) {
      const int row = p * 32 + srow;
      *(bf16x8*)&Ks[row * LS + sc8] =
          *(const bf16x8*)&qkv[(rb + kt * 64 + row) * ND3 + ND + h * HD + sc8];
      *(bf16x8*)&Vt[row * LS + sc8] =
          *(const bf16x8*)&vT[vbase + (long)row * ST + kt * 64 + sc8];
    }
    __syncthreads();

    f32x4 s_acc[4] = {};
#pragma unroll
    for (int kk = 0; kk < 2; ++kk) {
#pragma unroll
      for (int ni = 0; ni < 4; ++ni) {
        bf16x8 bk = *(const bf16x8*)&Ks[(ni * 16 + r) * LS + kk * 32 + g * 8];
        s_acc[ni] = MFMA(aq[kk], bk, s_acc[ni]);
      }
    }

    float mloc[4];
#pragma unroll
    for (int q = 0; q < 4; ++q) {
      float mx = fmaxf(fmaxf(s_acc[0][q], s_acc[1][q]), fmaxf(s_acc[2][q], s_acc[3][q]));
      mloc[q] = mx * 0.125f;
    }
#pragma unroll
    for (int mask = 1; mask < 16; mask <<= 1)
#pragma unroll
      for (int q = 0; q < 4; ++q)
        mloc[q] = fmaxf(mloc[q], __shfl_xor(mloc[q], mask, 64));

    float alpha[4], psum[4] = {0.f, 0.f, 0.f, 0.f};
#pragma unroll
    for (int q = 0; q < 4; ++q) {
      const float mn = fmaxf(m_run[q], mloc[q]);
      alpha[q] = __expf(m_run[q] - mn);
      m_run[q] = mn;
    }
#pragma unroll
    for (int ni = 0; ni < 4; ++ni)
#pragma unroll
      for (int q = 0; q < 4; ++q) {
        const float p = __expf(s_acc[ni][q] * 0.125f - m_run[q]);
        psum[q] += p;
        Ps[(w * 16 + g * 4 + q) * LS + ni * 16 + r] = f2bf(p);
      }
#pragma unroll
    for (int mask = 1; mask < 16; mask <<= 1)
#pragma unroll
      for (int q = 0; q < 4; ++q) psum[q] += __shfl_xor(psum[q], mask, 64);
#pragma unroll
    for (int q = 0; q < 4; ++q) l_run[q] = l_run[q] * alpha[q] + psum[q];
#pragma unroll
    for (int ni = 0; ni < 4; ++ni)
#pragma unroll
      for (int q = 0; q < 4; ++q) acc_o[ni][q] *= alpha[q];

    asm volatile("s_waitcnt lgkmcnt(0)" ::: "memory");
    __builtin_amdgcn_sched_barrier(0);

#pragma unroll
    for (int kk = 0; kk < 2; ++kk) {
      bf16x8 ap = *(const bf16x8*)&Ps[(w * 16 + r) * LS + kk * 32 + g * 8];
#pragma unroll
      for (int ni = 0; ni < 4; ++ni) {
        bf16x8 bv = *(const bf16x8*)&Vt[(ni * 16 + r) * LS + kk * 32 + g * 8];
        acc_o[ni] = MFMA(ap, bv, acc_o[ni]);
      }
    }
    __syncthreads();
  }

#pragma unroll
  for (int ni = 0; ni < 4; ++ni)
#pragma unroll
    for (int q = 0; q < 4; ++q) {
      const int row = q0 + w * 16 + g * 4 + q;
      const int col = h * HD + ni * 16 + r;
      y[(rb + row) * ND + col] = f2bf(acc_o[ni][q] / l_run[q]);
    }
}

// LayerNorm over D=768 (+optional residual add); writes fp32 and/or bf16.
template <bool RESID>
__global__ __launch_bounds__(256)
void ln_kernel(const float* __restrict__ in, const float* __restrict__ resid,
               const float* __restrict__ gamma, const float* __restrict__ beta,
               float* __restrict__ out_f, unsigned short* __restrict__ out_b)
{
  __shared__ float wred[8];
  const int row = blockIdx.x, tid = threadIdx.x;
  float v[3];
#pragma unroll
  for (int j = 0; j < 3; ++j) v[j] = in[(long)row * ND + tid + j * 256];
  float s = v[0] + v[1] + v[2];
#pragma unroll
  for (int m = 1; m < 64; m <<= 1) s += __shfl_xor(s, m, 64);
  if ((tid & 63) == 0) wred[tid >> 6] = s;
  __syncthreads();
  const float mean = (wred[0] + wred[1] + wred[2] + wred[3]) * (1.0f / ND);
  float d[3];
#pragma unroll
  for (int j = 0; j < 3; ++j) d[j] = v[j] - mean;
  float s2 = d[0] * d[0] + d[1] * d[1] + d[2] * d[2];
#pragma unroll
  for (int m = 1; m < 64; m <<= 1) s2 += __shfl_xor(s2, m, 64);
  if ((tid & 63) == 0) wred[4 + (tid >> 6)] = s2;
  __syncthreads();
  const float var = (wred[4] + wred[5] + wred[6] + wred[7]) * (1.0f / ND);
  const float rstd = rsqrtf(var + 1e-5f);
#pragma unroll
  for (int j = 0; j < 3; ++j) {
    const int c = tid + j * 256;
    float o = d[j] * rstd * gamma[c] + beta[c];
    if (RESID) o += resid[(long)row * ND + c];
    if (out_f) out_f[(long)row * ND + c] = o;
    if (out_b) out_b[(long)row * ND + c] = f2bf(o);
  }
}

__global__ __launch_bounds__(256)
void embed_kernel(const int* __restrict__ ids, const float* __restrict__ wte,
                  const float* __restrict__ wpe, float* __restrict__ x,
                  unsigned short* __restrict__ xb)
{
  const int t = blockIdx.x, tid = threadIdx.x;
  const int tok = ids[t];
  const int pos = t & (ST - 1);
#pragma unroll
  for (int j = 0; j < 3; ++j) {
    const int c = tid + j * 256;
    const float v = wte[(long)tok * ND + c] + wpe[(long)pos * ND + c];
    x[(long)t * ND + c] = v;
    xb[(long)t * ND + c] = f2bf(v);
  }
}

// fp32 [z][R][C] -> bf16 [z][C][R], 64(R)x32(C) tiles, coalesced both sides.
__global__ __launch_bounds__(256)
void transpose_bf16(const float* __restrict__ in, unsigned short* __restrict__ out,
                    int R, int C)
{
  __shared__ float tile[64][33];
  const long z = (long)blockIdx.z * R * C;
  const int c0 = blockIdx.x * 32, r0 = blockIdx.y * 64;
  const int tx = threadIdx.x & 31, ty = threadIdx.x >> 5;
#pragma unroll
  for (int j = 0; j < 8; ++j) {
    const int rr = r0 + j * 8 + ty, cc = c0 + tx;
    if (cc < C) tile[j * 8 + ty][tx] = in[z + (long)rr * C + cc];
  }
  __syncthreads();
  const int rx = threadIdx.x & 63, cy = threadIdx.x >> 6;
#pragma unroll
  for (int j = 0; j < 8; ++j) {
    const int cc = c0 + j * 4 + cy;
    if (cc < C) out[z + (long)cc * R + r0 + rx] = f2bf(tile[rx][j * 4 + cy]);
  }
}

extern "C" void kernel_launch(void* const* d_in, const int* in_sizes, int n_in,
                              void* d_out, int out_size, void* d_ws, size_t ws_size,
                              hipStream_t stream)
{
  const int*   ids    = (const int*)d_in[0];
  const float* wte    = (const float*)d_in[1];
  const float* wpe    = (const float*)d_in[2];
  const float* W_qkv  = (const float*)d_in[3];
  const float* b_qkv  = (const float*)d_in[4];
  const float* W_o    = (const float*)d_in[5];
  const float* b_o    = (const float*)d_in[6];
  const float* ln1_g  = (const float*)d_in[7];
  const float* ln1_b  = (const float*)d_in[8];
  const float* W1     = (const float*)d_in[9];
  const float* b1     = (const float*)d_in[10];
  const float* W2     = (const float*)d_in[11];
  const float* b2     = (const float*)d_in[12];
  const float* lnf_g  = (const float*)d_in[13];
  const float* lnf_b  = (const float*)d_in[14];
  const float* W_head = (const float*)d_in[15];
  const float* b_head = (const float*)d_in[16];
  float* out = (float*)d_out;
  (void)in_sizes; (void)n_in; (void)out_size; (void)ws_size;

  char* ws = (char*)d_ws;
  size_t off = 0;
  auto alloc = [&](size_t bytes) -> void* {
    void* p = (void*)(ws + off);
    off = (off + bytes + 255) & ~(size_t)255;
    return p;
  };
  unsigned short* wqkvT = (unsigned short*)alloc((size_t)NL * ND3 * ND * 2);
  unsigned short* woT   = (unsigned short*)alloc((size_t)NL * ND * ND * 2);
  unsigned short* w1T   = (unsigned short*)alloc((size_t)NL * NFF * ND * 2);
  unsigned short* w2T   = (unsigned short*)alloc((size_t)NL * ND * NFF * 2);
  unsigned short* whT   = (unsigned short*)alloc((size_t)NV * ND * 2);
  float*          xf    = (float*)alloc((size_t)NM * ND * 4);
  unsigned short* xb    = (unsigned short*)alloc((size_t)NM * ND * 2);
  unsigned short* qkvb  = (unsigned short*)alloc((size_t)NM * ND3 * 2);
  unsigned short* yb    = (unsigned short*)alloc((size_t)NM * ND * 2);
  float*          aof   = (float*)alloc((size_t)NM * ND * 4);
  unsigned short* h1b   = (unsigned short*)alloc((size_t)NM * NFF * 2);
  unsigned short* xlnb  = (unsigned short*)alloc((size_t)NM * ND * 2);
  unsigned short* vtb   = (unsigned short*)alloc((size_t)NB * NH * HD * ST * 2);

  dim3 tb(256);
  dim3 tb128(128);
  dim3 tb512(512);
  transpose_bf16<<<dim3(ND3 / 32, ND / 64, NL), tb, 0, stream>>>(W_qkv, wqkvT, ND, ND3);
  transpose_bf16<<<dim3(ND / 32, ND / 64, NL), tb, 0, stream>>>(W_o, woT, ND, ND);
  transpose_bf16<<<dim3(NFF / 32, ND / 64, NL), tb, 0, stream>>>(W1, w1T, ND, NFF);
  transpose_bf16<<<dim3(ND / 32, NFF / 64, NL), tb, 0, stream>>>(W2, w2T, NFF, ND);
  transpose_bf16<<<dim3((NV + 31) / 32, ND / 64, 1), tb, 0, stream>>>(W_head, whT, ND, NV);

  embed_kernel<<<dim3(NM), tb, 0, stream>>>(ids, wte, wpe, xf, xb);

  for (int l = 0; l < NL; ++l) {
    gemm_bt<EP_QKV, 128, 64, 2, 4, 64, 2><<<dim3(NM / 128, ND3 / 64), tb, 0, stream>>>(
        xb, wqkvT + (size_t)l * ND3 * ND, b_qkv + (size_t)l * ND3,
        nullptr, qkvb, nullptr, vtb, NM, ND3, ND);
    attn_kernel<<<dim3(ST / 64, NB * NH), tb, 0, stream>>>(qkvb, vtb, yb);
    gemm_bt<EP_PROJ, 64, 64, 2, 2, 64, 2><<<dim3(NM / 64, ND / 64), tb128, 0, stream>>>(
        yb, woT + (size_t)l * ND * ND, b_o + (size_t)l * ND,
        aof, nullptr, nullptr, nullptr, NM, ND, ND);
    ln_kernel<true><<<dim3(NM), tb, 0, stream>>>(
        aof, xf, ln1_g + (size_t)l * ND, ln1_b + (size_t)l * ND, xf, xb);
    gemm_bt<EP_FF1, 128, 64, 2, 4, 64, 2><<<dim3(NM / 128, NFF / 64), tb, 0, stream>>>(
        xb, w1T + (size_t)l * NFF * ND, b1 + (size_t)l * NFF,
        nullptr, h1b, nullptr, nullptr, NM, NFF, ND);
    gemm_bt<EP_FF2, 64, 64, 2, 2, 64, 2><<<dim3(NM / 64, ND / 64), tb128, 0, stream>>>(
        h1b, w2T + (size_t)l * ND * NFF, b2 + (size_t)l * ND,
        xf, xb, xf, nullptr, NM, ND, NFF);
  }
  ln_kernel<false><<<dim3(NM), tb, 0, stream>>>(xf, nullptr, lnf_g, lnf_b, nullptr, xlnb);
  gemm_head_8ph<<<dim3(NM / 256, (NV + 255) / 256), tb512, 0, stream>>>(
      xlnb, whT, b_head, out, NM, NV, ND);
}